// Round 1
// baseline (2059.308 us; speedup 1.0000x reference)
//
#include <hip/hip_runtime.h>

// SparseCoding fused persistent kernel.
// B=32768 rows, D_in=128, D_out=512, 10 RMSProp steps.
// One block (256 threads) owns RTILE=16 rows for the whole iteration:
//   x state in LDS (16x512 f32), a1/a2 in registers (per-thread (r,j) slots),
//   W streamed from global (L2-resident, 256 KB).
// Per step:
//   phase 1: d[r][i] = sum_j x[r][j]*W[j][i] - inp[r][i]   (i per-lane, coalesced W)
//   phase 2: gacc[r][j] = sum_i d[r][i]*W[j][i]            (j per-lane pair)
//   update : g = 2*gacc + 0.1*x*rsqrt(x^2+1e-6); RMSProp+momentum; x in LDS.

#define BSZ   32768
#define DIN   128
#define DOUT  512
#define RTILE 16
#define NSTEP 10

__global__ __launch_bounds__(256, 2)
void sc_fused(const float* __restrict__ inp, const float* __restrict__ W,
              float* __restrict__ out)
{
    __shared__ float x_lds[RTILE][DOUT];    // 32 KB
    __shared__ float d_lds[RTILE][DIN];     //  8 KB
    __shared__ float inp_lds[RTILE][DIN];   //  8 KB

    const int t = threadIdx.x;
    const int row0 = blockIdx.x * RTILE;

    // Per-thread RMSProp state for slots (r, j0), (r, j0+1), r = 0..15
    float a1[RTILE][2];
    float a2[RTILE][2];
#pragma unroll
    for (int r = 0; r < RTILE; ++r) {
        a1[r][0] = a1[r][1] = 0.f;
        a2[r][0] = a2[r][1] = 0.f;
    }

    // init x = 0, load inputs tile
    for (int k = t; k < RTILE * DOUT; k += 256) (&x_lds[0][0])[k] = 0.f;
    for (int k = t; k < RTILE * DIN;  k += 256) (&inp_lds[0][0])[k] = inp[row0 * DIN + k];
    __syncthreads();

    const int i_p1 = t & 127;        // phase-1 column (0..127)
    const int rg   = (t >> 7) * 8;   // phase-1 row group (0 or 8)
    const int j0   = 2 * t;          // phase-2/update column pair (0..510)

    for (int step = 0; step < NSTEP; ++step) {
        // ---- phase 1: d = x @ W - inp  (reduce over j = 0..511) ----
        {
            float acc[8];
#pragma unroll
            for (int rr = 0; rr < 8; ++rr) acc[rr] = 0.f;

            for (int j = 0; j < DOUT; j += 4) {
                const float w0 = W[(j + 0) * DIN + i_p1];
                const float w1 = W[(j + 1) * DIN + i_p1];
                const float w2 = W[(j + 2) * DIN + i_p1];
                const float w3 = W[(j + 3) * DIN + i_p1];
#pragma unroll
                for (int rr = 0; rr < 8; ++rr) {
                    const float4 xv = *(const float4*)&x_lds[rg + rr][j];  // LDS broadcast
                    acc[rr] = fmaf(xv.x, w0, acc[rr]);
                    acc[rr] = fmaf(xv.y, w1, acc[rr]);
                    acc[rr] = fmaf(xv.z, w2, acc[rr]);
                    acc[rr] = fmaf(xv.w, w3, acc[rr]);
                }
            }
#pragma unroll
            for (int rr = 0; rr < 8; ++rr)
                d_lds[rg + rr][i_p1] = acc[rr] - inp_lds[rg + rr][i_p1];
        }
        __syncthreads();

        // ---- phase 2: gacc = d @ W^T  (reduce over i = 0..127) + update ----
        {
            float acc[RTILE][2];
#pragma unroll
            for (int r = 0; r < RTILE; ++r) acc[r][0] = acc[r][1] = 0.f;

            for (int i = 0; i < DIN; i += 4) {
                const float4 wa = *(const float4*)&W[(j0 + 0) * DIN + i];
                const float4 wb = *(const float4*)&W[(j0 + 1) * DIN + i];
#pragma unroll
                for (int r = 0; r < RTILE; ++r) {
                    const float4 dv = *(const float4*)&d_lds[r][i];  // LDS broadcast
                    acc[r][0] = fmaf(dv.x, wa.x, acc[r][0]);
                    acc[r][0] = fmaf(dv.y, wa.y, acc[r][0]);
                    acc[r][0] = fmaf(dv.z, wa.z, acc[r][0]);
                    acc[r][0] = fmaf(dv.w, wa.w, acc[r][0]);
                    acc[r][1] = fmaf(dv.x, wb.x, acc[r][1]);
                    acc[r][1] = fmaf(dv.y, wb.y, acc[r][1]);
                    acc[r][1] = fmaf(dv.z, wb.z, acc[r][1]);
                    acc[r][1] = fmaf(dv.w, wb.w, acc[r][1]);
                }
            }

            // RMSProp + momentum update, x lives in LDS
#pragma unroll
            for (int r = 0; r < RTILE; ++r) {
#pragma unroll
                for (int c = 0; c < 2; ++c) {
                    const float xv  = x_lds[r][j0 + c];
                    const float g   = 2.f * acc[r][c] + 0.1f * xv * rsqrtf(xv * xv + 1e-6f);
                    const float na1 = 0.9f * a1[r][c] + 0.1f * g * g;
                    a1[r][c] = na1;
                    const float upd = 0.001f * g * rsqrtf(na1 + 1e-8f);
                    const float na2 = 0.9f * a2[r][c] - upd;
                    a2[r][c] = na2;
                    x_lds[r][j0 + c] = xv + 0.9f * na2 - upd;
                }
            }
            __syncthreads();
        }
    }

    // write final x
    for (int k = t; k < RTILE * DOUT; k += 256)
        out[row0 * DOUT + k] = (&x_lds[0][0])[k];
}

extern "C" void kernel_launch(void* const* d_in, const int* in_sizes, int n_in,
                              void* d_out, int out_size, void* d_ws, size_t ws_size,
                              hipStream_t stream) {
    const float* inputs = (const float*)d_in[0];
    const float* W      = (const float*)d_in[1];
    float* out          = (float*)d_out;

    sc_fused<<<dim3(BSZ / RTILE), dim3(256), 0, stream>>>(inputs, W, out);
}

// Round 9
// 1606.016 us; speedup vs baseline: 1.2822x; 1.2822x over previous
//
#include <hip/hip_runtime.h>

// SparseCoding fused persistent kernel, fp32 VALU (R9 = R1 tuned).
// MFMA split-precision path (R3-R8) abandoned: trajectory is chaotic w.r.t.
// ~1e-6 gradient noise; every MFMA variant plateaued at 2.4-3.3e-3 regardless
// of split precision (2-level bf16 / 2-level f16 / 3-level f16 / delta-form /
// fp64-init+Kahan). Only the fp32-VALU serial-K chain (R1) landed in-threshold
// (4.9e-4, 4x margin). R9 keeps R1's per-element arithmetic BIT-IDENTICAL
// (same serial accumulation order, same fmaf chains, same rsqrtf) and only
// changes scheduling/layout:
//  - 3 blocks/CU (was 2): 48KB LDS, __launch_bounds__(256,3) -> 12 waves/CU.
//  - phase-2 reads W^T (fp32, packed once into d_ws): 8B/lane coalesced
//    (R1 read W rows at 1024B thread-stride -> 64 cache lines per instr).
//  - pointer-disciplined indexing; unroll hints.

#define BSZ   32768
#define DIN   128
#define DOUT  512
#define RTILE 16
#define NSTEP 10
#define NBLOCKS (BSZ / RTILE)   // 2048

typedef __attribute__((ext_vector_type(2))) float f32x2;

// pack W^T fp32 into ws: Wt[i][j] = W[j][i]  (values identical -> phase-2
// arithmetic stays bit-identical to reading W rows)
__global__ void sc_packT(const float* __restrict__ W, float* __restrict__ Wt) {
    const int tid = blockIdx.x * blockDim.x + threadIdx.x;  // 0..65535
    const int j = tid >> 7;      // 0..511 (coalesced read of W row-major)
    const int i = tid & 127;     // 0..127
    Wt[i * DOUT + j] = W[j * DIN + i];
}

__global__ __launch_bounds__(256, 3)
void sc_fused(const float* __restrict__ inp, const float* __restrict__ W,
              const float* __restrict__ Wt, float* __restrict__ out)
{
    __shared__ float x_lds[RTILE][DOUT];    // 32 KB
    __shared__ float d_lds[RTILE][DIN];     //  8 KB
    __shared__ float inp_lds[RTILE][DIN];   //  8 KB

    const int t = threadIdx.x;
    const int row0 = blockIdx.x * RTILE;

    // Per-thread RMSProp state for slots (r, j0), (r, j0+1), r = 0..15
    float a1[RTILE][2];
    float a2[RTILE][2];
#pragma unroll
    for (int r = 0; r < RTILE; ++r) {
        a1[r][0] = a1[r][1] = 0.f;
        a2[r][0] = a2[r][1] = 0.f;
    }

    // init x = 0, load inputs tile (coalesced)
    for (int k = t; k < RTILE * DOUT; k += 256) (&x_lds[0][0])[k] = 0.f;
    for (int k = t; k < RTILE * DIN;  k += 256) (&inp_lds[0][0])[k] = inp[row0 * DIN + k];
    __syncthreads();

    const int i_p1 = t & 127;        // phase-1 column (0..127)
    const int rg   = (t >> 7) * 8;   // phase-1 row group (0 or 8)
    const int j0   = 2 * t;          // phase-2/update column pair (0..510)

    // thread-fixed base pointers (helps SGPR-base + imm-offset codegen)
    const float* __restrict__ wcol = W + i_p1;           // W[j][i_p1] = wcol[j*DIN]
    const float* __restrict__ wtj  = Wt + j0;            // Wt[i][j0]  = wtj[i*DOUT]

    for (int step = 0; step < NSTEP; ++step) {
        // ---- phase 1: d = x @ W - inp  (serial j-chain, identical to R1) ----
        {
            float acc[8];
#pragma unroll
            for (int rr = 0; rr < 8; ++rr) acc[rr] = 0.f;

#pragma unroll 2
            for (int j = 0; j < DOUT; j += 4) {
                const float w0 = wcol[(j + 0) * DIN];
                const float w1 = wcol[(j + 1) * DIN];
                const float w2 = wcol[(j + 2) * DIN];
                const float w3 = wcol[(j + 3) * DIN];
#pragma unroll
                for (int rr = 0; rr < 8; ++rr) {
                    const float4 xv = *(const float4*)&x_lds[rg + rr][j];  // LDS broadcast
                    acc[rr] = fmaf(xv.x, w0, acc[rr]);
                    acc[rr] = fmaf(xv.y, w1, acc[rr]);
                    acc[rr] = fmaf(xv.z, w2, acc[rr]);
                    acc[rr] = fmaf(xv.w, w3, acc[rr]);
                }
            }
#pragma unroll
            for (int rr = 0; rr < 8; ++rr)
                d_lds[rg + rr][i_p1] = acc[rr] - inp_lds[rg + rr][i_p1];
        }
        __syncthreads();

        // ---- phase 2: gacc = d @ W^T (serial i-chain, identical to R1) ----
        {
            float acc[RTILE][2];
#pragma unroll
            for (int r = 0; r < RTILE; ++r) acc[r][0] = acc[r][1] = 0.f;

#pragma unroll 2
            for (int i = 0; i < DIN; i += 4) {
                // wq[c] = (W[j0][i+c], W[j0+1][i+c]) -- same values as R1's
                // wa/wb reads, but coalesced 8B/lane via Wt.
                const f32x2 wq0 = *(const f32x2*)&wtj[(i + 0) * DOUT];
                const f32x2 wq1 = *(const f32x2*)&wtj[(i + 1) * DOUT];
                const f32x2 wq2 = *(const f32x2*)&wtj[(i + 2) * DOUT];
                const f32x2 wq3 = *(const f32x2*)&wtj[(i + 3) * DOUT];
#pragma unroll
                for (int r = 0; r < RTILE; ++r) {
                    const float4 dv = *(const float4*)&d_lds[r][i];  // LDS broadcast
                    acc[r][0] = fmaf(dv.x, wq0.x, acc[r][0]);
                    acc[r][0] = fmaf(dv.y, wq1.x, acc[r][0]);
                    acc[r][0] = fmaf(dv.z, wq2.x, acc[r][0]);
                    acc[r][0] = fmaf(dv.w, wq3.x, acc[r][0]);
                    acc[r][1] = fmaf(dv.x, wq0.y, acc[r][1]);
                    acc[r][1] = fmaf(dv.y, wq1.y, acc[r][1]);
                    acc[r][1] = fmaf(dv.z, wq2.y, acc[r][1]);
                    acc[r][1] = fmaf(dv.w, wq3.y, acc[r][1]);
                }
            }

            // RMSProp + momentum update (identical to R1), x lives in LDS
#pragma unroll
            for (int r = 0; r < RTILE; ++r) {
#pragma unroll
                for (int c = 0; c < 2; ++c) {
                    const float xv  = x_lds[r][j0 + c];
                    const float g   = 2.f * acc[r][c] + 0.1f * xv * rsqrtf(xv * xv + 1e-6f);
                    const float na1 = 0.9f * a1[r][c] + 0.1f * g * g;
                    a1[r][c] = na1;
                    const float upd = 0.001f * g * rsqrtf(na1 + 1e-8f);
                    const float na2 = 0.9f * a2[r][c] - upd;
                    a2[r][c] = na2;
                    x_lds[r][j0 + c] = xv + 0.9f * na2 - upd;
                }
            }
            __syncthreads();
        }
    }

    // write final x (coalesced)
    for (int k = t; k < RTILE * DOUT; k += 256)
        out[row0 * DOUT + k] = (&x_lds[0][0])[k];
}

extern "C" void kernel_launch(void* const* d_in, const int* in_sizes, int n_in,
                              void* d_out, int out_size, void* d_ws, size_t ws_size,
                              hipStream_t stream) {
    const float* inputs = (const float*)d_in[0];
    const float* W      = (const float*)d_in[1];
    float* out          = (float*)d_out;
    float* Wt           = (float*)d_ws;   // 256 KB fp32 W^T

    sc_packT<<<dim3(256), dim3(256), 0, stream>>>(W, Wt);
    sc_fused<<<dim3(NBLOCKS), dim3(256), 0, stream>>>(inputs, W, Wt, out);
}